// Round 16
// baseline (6472.671 us; speedup 1.0000x reference)
//
#include <hip/hip_runtime.h>

#define TOTA 153450
#define NGRP 10
#define CAND_CAP 4096
#define SENT (-3.0e38f)

// ---------------- helpers ----------------
__device__ __forceinline__ int lv_base(int lv) {
  switch (lv) { case 0: return 0; case 1: return 115200; case 2: return 144000;
                case 3: return 151200; default: return 153000; }
}
__device__ __forceinline__ int lv_of_anchor(int a) {
  if (a < 115200) return 0;
  if (a < 144000) return 1;
  if (a < 151200) return 2;
  if (a < 153000) return 3;
  return 4;
}
__device__ __forceinline__ int kk_of(int lv) { return lv == 4 ? 450 : 1000; }

// monotone u32 key for f32; larger key <=> larger float
__device__ __forceinline__ unsigned fkey32(float f) {
  unsigned u = __float_as_uint(f);
  return (u & 0x80000000u) ? ~u : (u | 0x80000000u);
}
__device__ __forceinline__ float inv_fkey32(unsigned k) {
  unsigned u = (k & 0x80000000u) ? (k & 0x7FFFFFFFu) : ~k;
  return __uint_as_float(u);
}

// correctly-rounded f32 transcendentals via f64
__device__ __forceinline__ float cr_expf(float x) { return (float)exp((double)x); }
__device__ __forceinline__ float cr_sigmoidf(float x) {
  float t = (float)exp(-(double)x);
  float d = 1.0f + t;
  return 1.0f / d;
}

// ---------------- one-time weight transpose: WT[k][co] = CW[co][k] ----------------
__global__ void transpose_w_kernel(const float* __restrict__ CW, float* __restrict__ WT) {
  int i = blockIdx.x*256 + threadIdx.x;
  if (i >= 2304*256) return;
  int co = i / 2304;
  int k  = i - co*2304;
  WT[(size_t)k*256 + co] = CW[i];
}

// ---------------- fused conv3x3 + bias + relu + 1x1 heads ----------------
// NUMERICS BITWISE-FROZEN (R10-passing model): per-output FMA chain in
// k=(ci,ky,kx) order with kc=384 panel commits (plain adds); einsum-SOP
// heads. R16: weights read DIRECT from L2-resident WT (16-lane broadcast) —
// no WS staging, no per-chunk barriers (2 barriers total, CCH=128 input
// chunks). Same chain order/commits/values — only data movement changed.
template<int PPT, int CCH>
__global__ __launch_bounds__(256) void conv_head_kernel(
    const float* __restrict__ WT, const float* __restrict__ CB,
    const float* __restrict__ LW, const float* __restrict__ LB,
    const float* __restrict__ RW, const float* __restrict__ RB,
    const float* __restrict__ Xall,
    float* __restrict__ outLog, float* __restrict__ outReg,
    int H, int W, int abase)
{
#pragma clang fp contract(off)
  constexpr int SPT = PPT*16;
  constexpr int XCOLS = SPT + 2;
  constexpr int SMEM = (3*CCH*XCOLS*4 > 31744) ? 3*CCH*XCOLS*4 : 31744;
  __shared__ __align__(16) char smem[SMEM];
  float* XS = (float*)smem;                    // [3][CCH][XCOLS]
  const int tid = threadIdx.x;
  const int sp = tid & 15;
  const int cg = tid >> 4;
  const int x0 = blockIdx.x * SPT;
  const int y  = blockIdx.y;
  const int img = blockIdx.z;
  const float* X = Xall + (size_t)img*256*H*W;
  float* oLog = outLog + (size_t)img*TOTA;       // [2][TOTA]
  float* oReg = outReg + (size_t)img*TOTA*4;     // [2][TOTA*4]
  const float4* WT4 = (const float4*)WT;

  float acc[PPT][16];
  float acc2[PPT][16];
#pragma unroll
  for (int p = 0; p < PPT; ++p)
#pragma unroll
    for (int i = 0; i < 16; ++i) { acc[p][i] = 0.f; acc2[p][i] = 0.f; }

  for (int c0 = 0; c0 < 256; c0 += CCH) {
    __syncthreads();
    // stage input chunk: XS[ry][ci_l][col], ix = x0+col-1, iy = y+ry-1
    for (int t = tid; t < 3*CCH*XCOLS; t += 256) {
      int col = t % XCOLS; int r = t / XCOLS;
      int ci_l = r % CCH, ry = r / CCH;
      int ix = x0 + col - 1, iy = y + ry - 1;
      float v = 0.f;
      if (ix >= 0 && ix < W && iy >= 0 && iy < H)
        v = X[((size_t)(c0+ci_l)*H + iy)*W + ix];
      XS[r*XCOLS + col] = v;
    }
    __syncthreads();
    for (int ci_l = 0; ci_l < CCH; ++ci_l) {
      int ch9 = (c0 + ci_l) * 9;
#pragma unroll
      for (int k9 = 0; k9 < 9; ++k9) {
        int kglob = ch9 + k9;
        if (kglob == 384 || kglob == 768 || kglob == 1152 ||
            kglob == 1536 || kglob == 1920) {
#pragma unroll
          for (int p = 0; p < PPT; ++p)
#pragma unroll
            for (int i = 0; i < 16; ++i) { acc2[p][i] = acc2[p][i] + acc[p][i]; acc[p][i] = 0.f; }
        }
        int ky = k9 / 3, kx = k9 - ky*3;
        const float* xb = &XS[(ky*CCH + ci_l)*XCOLS + sp + kx];
        float dxv[PPT];
#pragma unroll
        for (int p = 0; p < PPT; ++p) dxv[p] = xb[p*16];
        const float4* wr = WT4 + (size_t)kglob*64 + cg*4;   // direct L2 read (broadcast)
#pragma unroll
        for (int i = 0; i < 4; ++i) {
          float4 w4 = wr[i];
#pragma unroll
          for (int p = 0; p < PPT; ++p) {
            acc[p][4*i+0] = fmaf(w4.x, dxv[p], acc[p][4*i+0]);
            acc[p][4*i+1] = fmaf(w4.y, dxv[p], acc[p][4*i+1]);
            acc[p][4*i+2] = fmaf(w4.z, dxv[p], acc[p][4*i+2]);
            acc[p][4*i+3] = fmaf(w4.w, dxv[p], acc[p][4*i+3]);
          }
        }
      }
    }
  }
  __syncthreads();
  // head phase: PPT passes of 16 pixels; HS[256][16] + HWT[15][256]
  float* HS = (float*)smem;                    // 16384 B
  float* HWT = (float*)(smem + 16384);         // 15360 B
  for (int t = tid; t < 15*256; t += 256) {
    int o = t >> 8, c = t & 255;
    HWT[t] = (o < 3) ? LW[o*256 + c] : RW[(o-3)*256 + c];
  }
#pragma unroll
  for (int px = 0; px < PPT; ++px) {
    __syncthreads();
#pragma unroll
    for (int i = 0; i < 16; ++i) {
      float hsum = acc2[px][i] + acc[px][i];   // final panel commit
      float v = hsum + CB[cg*16 + i];
      HS[(cg*16 + i)*16 + sp] = v > 0.f ? v : 0.f;
    }
    __syncthreads();
    if (cg < 15) {
      const float* wr = &HWT[cg*256];
      float a2 = 0.f;
      for (int c = 0; c < 256; ++c) {
        float p = HS[c*16 + sp] * wr[c];   // separate rounding (no FMA)
        a2 = a2 + p;
      }
      int gx = x0 + px*16 + sp;
      if (gx < W) {
        int locg = y*W + gx;
        if (cg < 3) {
          oLog[abase + locg*3 + cg] = a2 + LB[cg];
        } else {
          int oo = cg - 3;
          oReg[(size_t)(abase + locg*3 + (oo >> 2))*4 + (oo & 3)] = a2 + RB[oo];
        }
      }
    }
  }
}

// ---------------- fast exact top-k: hist -> thresh -> collect -> sort ----------------
__global__ void hist_kernel(const float* __restrict__ logits, unsigned* __restrict__ hist) {
  int i = blockIdx.x*256 + threadIdx.x;
  if (i >= 2*TOTA) return;
  int img = i / TOTA, a = i - img*TOTA;
  int lv = lv_of_anchor(a);
  unsigned k = fkey32(logits[i]);
  atomicAdd(&hist[(size_t)(img*5+lv)*65536 + (k >> 16)], 1u);
}

__global__ __launch_bounds__(256) void thresh_kernel(const unsigned* __restrict__ hist,
                                                     int* __restrict__ meta) {
  int g = blockIdx.x;
  const unsigned* hg = hist + (size_t)g*65536;
  __shared__ unsigned part[256];
  int tid = threadIdx.x;
  unsigned s = 0;
  for (int b = tid*256; b < tid*256 + 256; ++b) s += hg[b];
  part[tid] = s;
  __syncthreads();
  if (tid == 0) {
    int k = kk_of(g % 5);
    unsigned cum = 0; int gsel = 0;
    for (int j = 255; j >= 0; --j) {
      if (cum + part[j] >= (unsigned)k) { gsel = j; break; }
      cum += part[j];
    }
    int B = gsel*256;
    for (int b = gsel*256 + 255; b >= gsel*256; --b) {
      unsigned h = hg[b];
      if (cum + h >= (unsigned)k) { B = b; break; }
      cum += h;
    }
    meta[g] = B;
  }
}

__global__ void collect_kernel(const float* __restrict__ logits, const int* __restrict__ meta,
                               int* __restrict__ ccnt, unsigned long long* __restrict__ cand) {
  int i = blockIdx.x*256 + threadIdx.x;
  if (i >= 2*TOTA) return;
  int img = i / TOTA, a = i - img*TOTA;
  int lv = lv_of_anchor(a);
  int g = img*5 + lv;
  unsigned k = fkey32(logits[i]);
  if ((int)(k >> 16) >= meta[g]) {
    int p = atomicAdd(&ccnt[g], 1);
    if (p < CAND_CAP) {
      unsigned idx = (unsigned)(a - lv_base(lv));
      cand[(size_t)g*CAND_CAP + p] =
          ((unsigned long long)k << 32) | (unsigned long long)(0xFFFFFFFFu ^ idx);
    }
  }
}

// bitonic sort candidates desc (key desc, idx asc); emit top-k (logit, idx)
__global__ __launch_bounds__(1024) void selsort_kernel(
    const int* __restrict__ ccnt, const unsigned long long* __restrict__ cand,
    float* __restrict__ sellk, unsigned* __restrict__ seli, int* __restrict__ selcnt)
{
  __shared__ unsigned long long KS[CAND_CAP];
  int g = blockIdx.x, tid = threadIdx.x;
  int n = ccnt[g]; if (n > CAND_CAP) n = CAND_CAP;
  for (int t = tid; t < CAND_CAP; t += 1024)
    KS[t] = (t < n) ? cand[(size_t)g*CAND_CAP + t] : 0ULL;
  __syncthreads();
  for (int k2 = 2; k2 <= CAND_CAP; k2 <<= 1)
    for (int j = k2 >> 1; j > 0; j >>= 1) {
      for (int t = tid; t < CAND_CAP/2; t += 1024) {
        int i = (t/j)*(2*j) + (t%j);
        int ix = i + j;
        bool up = ((i & k2) == 0);
        unsigned long long a = KS[i], b = KS[ix];
        if ((a < b) == up) { KS[i] = b; KS[ix] = a; }
      }
      __syncthreads();
    }
  int k = kk_of(g % 5);
  if (tid == 0) selcnt[g] = k;
  for (int t = tid; t < 1024; t += 1024) {
    if (t < k) {
      unsigned long long e = KS[t];
      sellk[(size_t)g*1024 + t] = inv_fkey32((unsigned)(e >> 32));
      seli[(size_t)g*1024 + t] = 0xFFFFFFFFu ^ (unsigned)(e & 0xFFFFFFFFULL);
    } else {
      sellk[(size_t)g*1024 + t] = SENT;
      seli[(size_t)g*1024 + t] = 0u;
    }
  }
}

// ---------------- f32 decode + clamp (per-op rounding, CR exp) + s32 scores ----------------
__global__ __launch_bounds__(1024) void decode_kernel(
    const unsigned* __restrict__ seli, const float* __restrict__ sellk,
    const int* __restrict__ selcnt,
    const float* __restrict__ reg, const float* __restrict__ imsz,
    const float* __restrict__ p0, const float* __restrict__ p1, const float* __restrict__ p2,
    const float* __restrict__ p3, const float* __restrict__ p4,
    float* __restrict__ boxesF, float* __restrict__ selv32)
{
#pragma clang fp contract(off)
  int g = blockIdx.x, t = threadIdx.x;
  int img = g/5, lv = g - img*5;
  int k = selcnt[g];
  float b0 = 0, b1 = 0, b2 = 0, b3 = 0;
  float sv = SENT;
  if (t < k) {
    unsigned aidx = seli[(size_t)g*1024 + t];
    const float* pr;
    switch (lv) { case 0: pr = p0; break; case 1: pr = p1; break; case 2: pr = p2; break;
                  case 3: pr = p3; break; default: pr = p4; }
    pr += (size_t)aidx*4;
    const float* rg = reg + ((size_t)img*TOTA + lv_base(lv) + aidx)*4;
    float q0 = pr[0], q1 = pr[1], q2 = pr[2], q3 = pr[3];
    float pw = q2 - q0, ph = q3 - q1;
    float pcx = q0 + 0.5f*pw, pcy = q1 + 0.5f*ph;
    float t0 = rg[0]*pw, t1 = rg[1]*ph;
    float cx = pcx + t0, cy = pcy + t1;
    float e2 = cr_expf(rg[2]);
    float e3 = cr_expf(rg[3]);
    float bw = pw*e2, bh = ph*e3;
    float x1 = cx - bw*0.5f, y1 = cy - bh*0.5f, x2 = cx + bw*0.5f, y2 = cy + bh*0.5f;
    float mh = imsz[img*2 + 0], mw = imsz[img*2 + 1];
    b0 = fminf(fmaxf(x1, 0.f), mw);
    b1 = fminf(fmaxf(y1, 0.f), mh);
    b2 = fminf(fmaxf(x2, 0.f), mw);
    b3 = fminf(fmaxf(y2, 0.f), mh);
    sv = cr_sigmoidf(sellk[(size_t)g*1024 + t]);
  }
  float* o = boxesF + ((size_t)g*1024 + t)*4;
  o[0] = b0; o[1] = b1; o[2] = b2; o[3] = b3;
  selv32[(size_t)g*1024 + t] = sv;
}

// ---------------- global max over clamped boxes (all >= 0) ----------------
__global__ void maxbox_kernel(const float* __restrict__ boxesF, unsigned* __restrict__ maxbuf) {
  int i = blockIdx.x*1024 + threadIdx.x;
  if (i < NGRP*1024*4) {
    float v = boxesF[i];
    atomicMax(maxbuf, __float_as_uint(v));
  }
}

// ---------------- NMS: parallel IoU bitmask (same f32 exprs) + serial scan ----------------
__global__ __launch_bounds__(256) void mask_kernel(
    const float* __restrict__ boxesF, const int* __restrict__ selcnt,
    const unsigned* __restrict__ maxbuf, unsigned long long* __restrict__ supm)
{
#pragma clang fp contract(off)
  __shared__ float4 BS[1024];
  __shared__ float AR[1024];
  int g = blockIdx.y;
  int i = blockIdx.x*16 + (threadIdx.x >> 4);
  int w = threadIdx.x & 15;
  int img = g/5, lv = g - img*5;
  int k = selcnt[g];
  float mx1 = __uint_as_float(*maxbuf) + 1.0f;
  float offv = (float)(img*10 + lv) * mx1;
  for (int t = threadIdx.x; t < 1024; t += 256) {
    float4 b = ((const float4*)boxesF)[(size_t)g*1024 + t];
    b.x = b.x + offv; b.y = b.y + offv; b.z = b.z + offv; b.w = b.w + offv;
    BS[t] = b;
    float dw = b.z - b.x, dh = b.w - b.y;
    AR[t] = dw*dh;
  }
  __syncthreads();
  unsigned long long m = 0ULL;
  if (i < k) {
    float4 bi = BS[i]; float ai = AR[i];
    int jbase = w*64;
    for (int jj = 0; jj < 64; ++jj) {
      int j = jbase + jj;
      if (j > i && j < k) {
        float4 bj = BS[j];
        float ix1 = fmaxf(bi.x, bj.x), iy1 = fmaxf(bi.y, bj.y);
        float ix2 = fminf(bi.z, bj.z), iy2 = fminf(bi.w, bj.w);
        float d1 = fmaxf(ix2 - ix1, 0.f), d2 = fmaxf(iy2 - iy1, 0.f);
        float inter = d1*d2;
        float un = ai + AR[j];
        un = un - inter;
        float iou = inter / fmaxf(un, 1e-9f);
        if (iou > 0.7f) m |= (1ULL << jj);
      }
    }
  }
  supm[((size_t)g*1024 + i)*16 + w] = m;
}

__global__ __launch_bounds__(64) void nms_scan_kernel(
    const unsigned long long* __restrict__ supm, const int* __restrict__ selcnt,
    unsigned long long* __restrict__ keepw)
{
  __shared__ unsigned long long rem[16];
  int g = blockIdx.x, l = threadIdx.x;
  if (l < 16) rem[l] = 0ULL;
  __syncthreads();
  int k = selcnt[g];
  for (int i = 0; i < k; ++i) {
    bool sup = (rem[i >> 6] >> (i & 63)) & 1ULL;
    __syncthreads();
    if (!sup && l < 16) rem[l] |= supm[((size_t)g*1024 + i)*16 + l];
    __syncthreads();
  }
  if (l < 16) keepw[g*16 + l] = ~rem[l];
}

// ---------------- per-image merge: packed-key bitonic sort, emit top-1000 ----------------
__global__ __launch_bounds__(1024) void final_kernel(
    const float* __restrict__ selv32, const int* __restrict__ selcnt,
    const unsigned long long* __restrict__ keepw, const float* __restrict__ boxesF,
    float* __restrict__ outB, float* __restrict__ outI)
{
  extern __shared__ unsigned long long S[];
  int img = blockIdx.x, tid = threadIdx.x;
  for (int t = tid; t < 8192; t += 1024) {
    unsigned long long key = 0ULL;
    if (t < 5000) {
      int lv = t / 1000, r = t - lv*1000;
      int g = img*5 + lv;
      if (r < selcnt[g] && ((keepw[g*16 + (r >> 6)] >> (r & 63)) & 1ULL)) {
        float sv = selv32[(size_t)g*1024 + r];
        // score desc, then slot (concat position) asc = stable argsort
        key = ((unsigned long long)fkey32(sv) << 32) |
              (unsigned long long)(0xFFFFFFFFu ^ (unsigned)t);
      }
    }
    S[t] = key;
  }
  __syncthreads();
  for (int k2 = 2; k2 <= 8192; k2 <<= 1)
    for (int j = k2 >> 1; j > 0; j >>= 1) {
      for (int t = tid; t < 4096; t += 1024) {
        int i = (t/j)*(2*j) + (t%j);
        int ix = i + j;
        bool up = ((i & k2) == 0);
        unsigned long long a = S[i], b = S[ix];
        if ((a < b) == up) { S[i] = b; S[ix] = a; }
      }
      __syncthreads();
    }
  for (int t = tid; t < 1000; t += 1024) {
    unsigned long long key = S[t];
    float4 bo = make_float4(0.f, 0.f, 0.f, 0.f);
    float ii = -1.f;
    if (key != 0ULL) {
      unsigned slot = 0xFFFFFFFFu ^ (unsigned)(key & 0xFFFFFFFFULL);
      int lv = slot / 1000, r = slot - lv*1000;
      const float* bp = boxesF + (((size_t)(img*5 + lv))*1024 + r)*4;
      bo = make_float4(bp[0], bp[1], bp[2], bp[3]);
      ii = (float)img;
    }
    ((float4*)outB)[img*1000 + t] = bo;
    outI[img*1000 + t] = ii;
  }
}

// ---------------- launch ----------------
extern "C" void kernel_launch(void* const* d_in, const int* in_sizes, int n_in,
                              void* d_out, int out_size, void* d_ws, size_t ws_size,
                              hipStream_t stream)
{
  const int LV_H[5]  = {160, 80, 40, 20, 10};
  const int LV_W[5]  = {240, 120, 60, 30, 15};
  const int LV_BASE_[5] = {0, 115200, 144000, 151200, 153000};

  const float* fm[5]; const float* pri[5];
  if (n_in >= 17 && in_sizes[1] == 460800) {
    for (int i = 0; i < 5; ++i) { fm[i] = (const float*)d_in[2*i]; pri[i] = (const float*)d_in[2*i+1]; }
  } else {
    for (int i = 0; i < 5; ++i) { fm[i] = (const float*)d_in[i]; pri[i] = (const float*)d_in[5+i]; }
  }
  const float* imsz  = (const float*)d_in[10];
  const float* convw = (const float*)d_in[11];
  const float* convb = (const float*)d_in[12];
  const float* logw  = (const float*)d_in[13];
  const float* logb  = (const float*)d_in[14];
  const float* regw  = (const float*)d_in[15];
  const float* regb  = (const float*)d_in[16];

  char* ws = (char*)d_ws;
  size_t off = 0;
  auto nxt = [&](size_t b) { size_t o = off; off = (off + b + 255) & ~(size_t)255; return o; };
  float* WT        = (float*)(ws + nxt((size_t)2304*256*4));
  float* logitsF   = (float*)(ws + nxt((size_t)2*TOTA*4));
  float* regF      = (float*)(ws + nxt((size_t)2*TOTA*4*4));
  unsigned* hist   = (unsigned*)(ws + nxt((size_t)NGRP*65536*4));
  int* meta        = (int*)(ws + nxt((size_t)NGRP*4));
  int* ccnt        = (int*)(ws + nxt((size_t)NGRP*4));
  unsigned long long* cand = (unsigned long long*)(ws + nxt((size_t)NGRP*CAND_CAP*8));
  float* sellk     = (float*)(ws + nxt((size_t)NGRP*1024*4));
  unsigned* seli   = (unsigned*)(ws + nxt((size_t)NGRP*1024*4));
  int* selcnt      = (int*)(ws + nxt((size_t)NGRP*4));
  float* selv32    = (float*)(ws + nxt((size_t)NGRP*1024*4));
  float* boxesF    = (float*)(ws + nxt((size_t)NGRP*1024*4*4));
  unsigned* maxbuf = (unsigned*)(ws + nxt(4));
  unsigned long long* supm  = (unsigned long long*)(ws + nxt((size_t)NGRP*1024*16*8));
  unsigned long long* keepw = (unsigned long long*)(ws + nxt((size_t)NGRP*16*8));
  if (off > ws_size) return;

  hipMemsetAsync(hist, 0, (size_t)NGRP*65536*4, stream);
  hipMemsetAsync(ccnt, 0, NGRP*4, stream);
  hipMemsetAsync(maxbuf, 0, 4, stream);

  transpose_w_kernel<<<2304, 256, 0, stream>>>(convw, WT);

  // fmap tensors are [N=2, C, H, W]; blockIdx.z selects the image.
  for (int lv = 0; lv < 5; ++lv) {
    dim3 grid((LV_W[lv] + 31)/32, LV_H[lv], 2);
    conv_head_kernel<2,128><<<grid, 256, 0, stream>>>(
        WT, convb, logw, logb, regw, regb, fm[lv],
        logitsF, regF, LV_H[lv], LV_W[lv], LV_BASE_[lv]);
  }
  int tot = 2*TOTA;
  hist_kernel<<<(tot + 255)/256, 256, 0, stream>>>(logitsF, hist);
  thresh_kernel<<<NGRP, 256, 0, stream>>>(hist, meta);
  collect_kernel<<<(tot + 255)/256, 256, 0, stream>>>(logitsF, meta, ccnt, cand);
  selsort_kernel<<<NGRP, 1024, 0, stream>>>(ccnt, cand, sellk, seli, selcnt);
  decode_kernel<<<NGRP, 1024, 0, stream>>>(seli, sellk, selcnt, regF, imsz,
      pri[0], pri[1], pri[2], pri[3], pri[4], boxesF, selv32);
  maxbox_kernel<<<(NGRP*1024*4 + 1023)/1024, 1024, 0, stream>>>(boxesF, maxbuf);
  mask_kernel<<<dim3(64, NGRP), 256, 0, stream>>>(boxesF, selcnt, maxbuf, supm);
  nms_scan_kernel<<<NGRP, 64, 0, stream>>>(supm, selcnt, keepw);
  final_kernel<<<2, 1024, 65536, stream>>>(selv32, selcnt, keepw, boxesF,
      (float*)d_out, (float*)d_out + 8000);
}

// Round 17
// 3862.338 us; speedup vs baseline: 1.6758x; 1.6758x over previous
//
#include <hip/hip_runtime.h>

#define TOTA 153450
#define NGRP 10
#define CK 4
#define CAND_CAP 4096
#define SENT (-3.0e38f)

// ---------------- helpers ----------------
__device__ __forceinline__ int lv_base(int lv) {
  switch (lv) { case 0: return 0; case 1: return 115200; case 2: return 144000;
                case 3: return 151200; default: return 153000; }
}
__device__ __forceinline__ int lv_of_anchor(int a) {
  if (a < 115200) return 0;
  if (a < 144000) return 1;
  if (a < 151200) return 2;
  if (a < 153000) return 3;
  return 4;
}
__device__ __forceinline__ int kk_of(int lv) { return lv == 4 ? 450 : 1000; }

// monotone u32 key for f32; larger key <=> larger float
__device__ __forceinline__ unsigned fkey32(float f) {
  unsigned u = __float_as_uint(f);
  return (u & 0x80000000u) ? ~u : (u | 0x80000000u);
}
__device__ __forceinline__ float inv_fkey32(unsigned k) {
  unsigned u = (k & 0x80000000u) ? (k & 0x7FFFFFFFu) : ~k;
  return __uint_as_float(u);
}

// correctly-rounded f32 transcendentals via f64
__device__ __forceinline__ float cr_expf(float x) { return (float)exp((double)x); }
__device__ __forceinline__ float cr_sigmoidf(float x) {
  float t = (float)exp(-(double)x);
  float d = 1.0f + t;
  return 1.0f / d;
}

// ---------------- one-time weight transpose: WT[k][co] = CW[co][k] ----------------
__global__ void transpose_w_kernel(const float* __restrict__ CW, float* __restrict__ WT) {
  int i = blockIdx.x*256 + threadIdx.x;
  if (i >= 2304*256) return;
  int co = i / 2304;
  int k  = i - co*2304;
  WT[(size_t)k*256 + co] = CW[i];
}

// ---------------- fused conv3x3 + bias + relu + 1x1 heads ----------------
// NUMERICS BITWISE-FROZEN (R10-passing model): per-output FMA chain in
// k=(ci,ky,kx) order with kc=384 panel commits (plain adds); einsum-SOP
// heads. R17: revert to R15's LDS weight staging (R16's direct-L2 reads
// were latency-bound, -2.1x); lv0 uses PPT=3 (SPT=48, exact 240 tiling,
// 1600 blocks, 48 FMA per ~7 ds-reads -> VALU-bound).
template<int PPT>
__global__ __launch_bounds__(256) void conv_head_kernel(
    const float* __restrict__ WT, const float* __restrict__ CB,
    const float* __restrict__ LW, const float* __restrict__ LB,
    const float* __restrict__ RW, const float* __restrict__ RB,
    const float* __restrict__ Xall,
    float* __restrict__ outLog, float* __restrict__ outReg,
    int H, int W, int abase)
{
#pragma clang fp contract(off)
  constexpr int SPT = PPT*16;
  constexpr int XCOLS = SPT + 2;
  constexpr int SMEM0 = CK*9*256*4 + 3*CK*XCOLS*4;
  constexpr int SMEM = (SMEM0 > 31744) ? SMEM0 : 31744;
  __shared__ __align__(16) char smem[SMEM];
  float* WS = (float*)smem;                    // conv: [CK*9][256]
  float* XS = (float*)(smem + CK*9*256*4);     // conv: [3*CK][XCOLS]
  const int tid = threadIdx.x;
  const int sp = tid & 15;
  const int cg = tid >> 4;
  const int x0 = blockIdx.x * SPT;
  const int y  = blockIdx.y;
  const int img = blockIdx.z;
  const float* X = Xall + (size_t)img*256*H*W;
  float* oLog = outLog + (size_t)img*TOTA;       // [2][TOTA]
  float* oReg = outReg + (size_t)img*TOTA*4;     // [2][TOTA*4]

  float acc[PPT][16];
  float acc2[PPT][16];
#pragma unroll
  for (int p = 0; p < PPT; ++p)
#pragma unroll
    for (int i = 0; i < 16; ++i) { acc[p][i] = 0.f; acc2[p][i] = 0.f; }

  for (int c0 = 0; c0 < 256; c0 += CK) {
    __syncthreads();
    // coalesced weight staging: 2304 float4s
    {
      const float4* wsrc = (const float4*)(WT + (size_t)c0*9*256);
      float4* wdst = (float4*)WS;
#pragma unroll
      for (int r = 0; r < 9; ++r)
        wdst[r*256 + tid] = wsrc[r*256 + tid];
    }
    // input strip: XS[ry*CK+ci][col], col -> ix = x0+col-1, 3 rows halo
    for (int t = tid; t < 3*CK*XCOLS; t += 256) {
      int col = t % XCOLS; int r = t / XCOLS;
      int ci = r % CK, ry = r / CK;
      int ix = x0 + col - 1, iy = y + ry - 1;
      float v = 0.f;
      if (ix >= 0 && ix < W && iy >= 0 && iy < H)
        v = X[((c0+ci)*H + iy)*W + ix];
      XS[r*XCOLS + col] = v;
    }
    __syncthreads();
#pragma unroll
    for (int ci = 0; ci < CK; ++ci) {
      int ch9 = (c0 + ci) * 9;
#pragma unroll
      for (int k9 = 0; k9 < 9; ++k9) {
        int kglob = ch9 + k9;
        if (kglob == 384 || kglob == 768 || kglob == 1152 ||
            kglob == 1536 || kglob == 1920) {
#pragma unroll
          for (int p = 0; p < PPT; ++p)
#pragma unroll
            for (int i = 0; i < 16; ++i) { acc2[p][i] = acc2[p][i] + acc[p][i]; acc[p][i] = 0.f; }
        }
        int ky = k9 / 3, kx = k9 - ky*3;
        const float* xb = &XS[(ky*CK + ci)*XCOLS + sp + kx];
        float dxv[PPT];
#pragma unroll
        for (int p = 0; p < PPT; ++p) dxv[p] = xb[p*16];
        const float* wr = &WS[(ci*9 + k9)*256 + cg*16];
#pragma unroll
        for (int i = 0; i < 16; i += 4) {
          float4 w4 = *(const float4*)(wr + i);
#pragma unroll
          for (int p = 0; p < PPT; ++p) {
            acc[p][i+0] = fmaf(w4.x, dxv[p], acc[p][i+0]);
            acc[p][i+1] = fmaf(w4.y, dxv[p], acc[p][i+1]);
            acc[p][i+2] = fmaf(w4.z, dxv[p], acc[p][i+2]);
            acc[p][i+3] = fmaf(w4.w, dxv[p], acc[p][i+3]);
          }
        }
      }
    }
  }
  __syncthreads();
  // head phase: PPT passes of 16 pixels; HS[256][16] + HWT[15][256]
  float* HS = (float*)smem;                    // 16384 B
  float* HWT = (float*)(smem + 16384);         // 15360 B
  for (int t = tid; t < 15*256; t += 256) {
    int o = t >> 8, c = t & 255;
    HWT[t] = (o < 3) ? LW[o*256 + c] : RW[(o-3)*256 + c];
  }
#pragma unroll
  for (int px = 0; px < PPT; ++px) {
    __syncthreads();
#pragma unroll
    for (int i = 0; i < 16; ++i) {
      float hsum = acc2[px][i] + acc[px][i];   // final panel commit
      float v = hsum + CB[cg*16 + i];
      HS[(cg*16 + i)*16 + sp] = v > 0.f ? v : 0.f;
    }
    __syncthreads();
    if (cg < 15) {
      const float* wr = &HWT[cg*256];
      float a2 = 0.f;
      for (int c = 0; c < 256; ++c) {
        float p = HS[c*16 + sp] * wr[c];   // separate rounding (no FMA)
        a2 = a2 + p;
      }
      int gx = x0 + px*16 + sp;
      if (gx < W) {
        int locg = y*W + gx;
        if (cg < 3) {
          oLog[abase + locg*3 + cg] = a2 + LB[cg];
        } else {
          int oo = cg - 3;
          oReg[(size_t)(abase + locg*3 + (oo >> 2))*4 + (oo & 3)] = a2 + RB[oo];
        }
      }
    }
  }
}

// ---------------- fast exact top-k: hist -> thresh -> collect -> sort ----------------
__global__ void hist_kernel(const float* __restrict__ logits, unsigned* __restrict__ hist) {
  int i = blockIdx.x*256 + threadIdx.x;
  if (i >= 2*TOTA) return;
  int img = i / TOTA, a = i - img*TOTA;
  int lv = lv_of_anchor(a);
  unsigned k = fkey32(logits[i]);
  atomicAdd(&hist[(size_t)(img*5+lv)*65536 + (k >> 16)], 1u);
}

__global__ __launch_bounds__(256) void thresh_kernel(const unsigned* __restrict__ hist,
                                                     int* __restrict__ meta) {
  int g = blockIdx.x;
  const unsigned* hg = hist + (size_t)g*65536;
  __shared__ unsigned part[256];
  int tid = threadIdx.x;
  unsigned s = 0;
  for (int b = tid*256; b < tid*256 + 256; ++b) s += hg[b];
  part[tid] = s;
  __syncthreads();
  if (tid == 0) {
    int k = kk_of(g % 5);
    unsigned cum = 0; int gsel = 0;
    for (int j = 255; j >= 0; --j) {
      if (cum + part[j] >= (unsigned)k) { gsel = j; break; }
      cum += part[j];
    }
    int B = gsel*256;
    for (int b = gsel*256 + 255; b >= gsel*256; --b) {
      unsigned h = hg[b];
      if (cum + h >= (unsigned)k) { B = b; break; }
      cum += h;
    }
    meta[g] = B;
  }
}

__global__ void collect_kernel(const float* __restrict__ logits, const int* __restrict__ meta,
                               int* __restrict__ ccnt, unsigned long long* __restrict__ cand) {
  int i = blockIdx.x*256 + threadIdx.x;
  if (i >= 2*TOTA) return;
  int img = i / TOTA, a = i - img*TOTA;
  int lv = lv_of_anchor(a);
  int g = img*5 + lv;
  unsigned k = fkey32(logits[i]);
  if ((int)(k >> 16) >= meta[g]) {
    int p = atomicAdd(&ccnt[g], 1);
    if (p < CAND_CAP) {
      unsigned idx = (unsigned)(a - lv_base(lv));
      cand[(size_t)g*CAND_CAP + p] =
          ((unsigned long long)k << 32) | (unsigned long long)(0xFFFFFFFFu ^ idx);
    }
  }
}

// bitonic sort candidates desc (key desc, idx asc); emit top-k (logit, idx)
__global__ __launch_bounds__(1024) void selsort_kernel(
    const int* __restrict__ ccnt, const unsigned long long* __restrict__ cand,
    float* __restrict__ sellk, unsigned* __restrict__ seli, int* __restrict__ selcnt)
{
  __shared__ unsigned long long KS[CAND_CAP];
  int g = blockIdx.x, tid = threadIdx.x;
  int n = ccnt[g]; if (n > CAND_CAP) n = CAND_CAP;
  for (int t = tid; t < CAND_CAP; t += 1024)
    KS[t] = (t < n) ? cand[(size_t)g*CAND_CAP + t] : 0ULL;
  __syncthreads();
  for (int k2 = 2; k2 <= CAND_CAP; k2 <<= 1)
    for (int j = k2 >> 1; j > 0; j >>= 1) {
      for (int t = tid; t < CAND_CAP/2; t += 1024) {
        int i = (t/j)*(2*j) + (t%j);
        int ix = i + j;
        bool up = ((i & k2) == 0);
        unsigned long long a = KS[i], b = KS[ix];
        if ((a < b) == up) { KS[i] = b; KS[ix] = a; }
      }
      __syncthreads();
    }
  int k = kk_of(g % 5);
  if (tid == 0) selcnt[g] = k;
  for (int t = tid; t < 1024; t += 1024) {
    if (t < k) {
      unsigned long long e = KS[t];
      sellk[(size_t)g*1024 + t] = inv_fkey32((unsigned)(e >> 32));
      seli[(size_t)g*1024 + t] = 0xFFFFFFFFu ^ (unsigned)(e & 0xFFFFFFFFULL);
    } else {
      sellk[(size_t)g*1024 + t] = SENT;
      seli[(size_t)g*1024 + t] = 0u;
    }
  }
}

// ---------------- f32 decode + clamp (per-op rounding, CR exp) + s32 scores ----------------
__global__ __launch_bounds__(1024) void decode_kernel(
    const unsigned* __restrict__ seli, const float* __restrict__ sellk,
    const int* __restrict__ selcnt,
    const float* __restrict__ reg, const float* __restrict__ imsz,
    const float* __restrict__ p0, const float* __restrict__ p1, const float* __restrict__ p2,
    const float* __restrict__ p3, const float* __restrict__ p4,
    float* __restrict__ boxesF, float* __restrict__ selv32)
{
#pragma clang fp contract(off)
  int g = blockIdx.x, t = threadIdx.x;
  int img = g/5, lv = g - img*5;
  int k = selcnt[g];
  float b0 = 0, b1 = 0, b2 = 0, b3 = 0;
  float sv = SENT;
  if (t < k) {
    unsigned aidx = seli[(size_t)g*1024 + t];
    const float* pr;
    switch (lv) { case 0: pr = p0; break; case 1: pr = p1; break; case 2: pr = p2; break;
                  case 3: pr = p3; break; default: pr = p4; }
    pr += (size_t)aidx*4;
    const float* rg = reg + ((size_t)img*TOTA + lv_base(lv) + aidx)*4;
    float q0 = pr[0], q1 = pr[1], q2 = pr[2], q3 = pr[3];
    float pw = q2 - q0, ph = q3 - q1;
    float pcx = q0 + 0.5f*pw, pcy = q1 + 0.5f*ph;
    float t0 = rg[0]*pw, t1 = rg[1]*ph;
    float cx = pcx + t0, cy = pcy + t1;
    float e2 = cr_expf(rg[2]);
    float e3 = cr_expf(rg[3]);
    float bw = pw*e2, bh = ph*e3;
    float x1 = cx - bw*0.5f, y1 = cy - bh*0.5f, x2 = cx + bw*0.5f, y2 = cy + bh*0.5f;
    float mh = imsz[img*2 + 0], mw = imsz[img*2 + 1];
    b0 = fminf(fmaxf(x1, 0.f), mw);
    b1 = fminf(fmaxf(y1, 0.f), mh);
    b2 = fminf(fmaxf(x2, 0.f), mw);
    b3 = fminf(fmaxf(y2, 0.f), mh);
    sv = cr_sigmoidf(sellk[(size_t)g*1024 + t]);
  }
  float* o = boxesF + ((size_t)g*1024 + t)*4;
  o[0] = b0; o[1] = b1; o[2] = b2; o[3] = b3;
  selv32[(size_t)g*1024 + t] = sv;
}

// ---------------- global max over clamped boxes (all >= 0) ----------------
__global__ void maxbox_kernel(const float* __restrict__ boxesF, unsigned* __restrict__ maxbuf) {
  int i = blockIdx.x*1024 + threadIdx.x;
  if (i < NGRP*1024*4) {
    float v = boxesF[i];
    atomicMax(maxbuf, __float_as_uint(v));
  }
}

// ---------------- NMS: parallel IoU bitmask (same f32 exprs) + serial scan ----------------
__global__ __launch_bounds__(256) void mask_kernel(
    const float* __restrict__ boxesF, const int* __restrict__ selcnt,
    const unsigned* __restrict__ maxbuf, unsigned long long* __restrict__ supm)
{
#pragma clang fp contract(off)
  __shared__ float4 BS[1024];
  __shared__ float AR[1024];
  int g = blockIdx.y;
  int i = blockIdx.x*16 + (threadIdx.x >> 4);
  int w = threadIdx.x & 15;
  int img = g/5, lv = g - img*5;
  int k = selcnt[g];
  float mx1 = __uint_as_float(*maxbuf) + 1.0f;
  float offv = (float)(img*10 + lv) * mx1;
  for (int t = threadIdx.x; t < 1024; t += 256) {
    float4 b = ((const float4*)boxesF)[(size_t)g*1024 + t];
    b.x = b.x + offv; b.y = b.y + offv; b.z = b.z + offv; b.w = b.w + offv;
    BS[t] = b;
    float dw = b.z - b.x, dh = b.w - b.y;
    AR[t] = dw*dh;
  }
  __syncthreads();
  unsigned long long m = 0ULL;
  if (i < k) {
    float4 bi = BS[i]; float ai = AR[i];
    int jbase = w*64;
    for (int jj = 0; jj < 64; ++jj) {
      int j = jbase + jj;
      if (j > i && j < k) {
        float4 bj = BS[j];
        float ix1 = fmaxf(bi.x, bj.x), iy1 = fmaxf(bi.y, bj.y);
        float ix2 = fminf(bi.z, bj.z), iy2 = fminf(bi.w, bj.w);
        float d1 = fmaxf(ix2 - ix1, 0.f), d2 = fmaxf(iy2 - iy1, 0.f);
        float inter = d1*d2;
        float un = ai + AR[j];
        un = un - inter;
        float iou = inter / fmaxf(un, 1e-9f);
        if (iou > 0.7f) m |= (1ULL << jj);
      }
    }
  }
  supm[((size_t)g*1024 + i)*16 + w] = m;
}

__global__ __launch_bounds__(64) void nms_scan_kernel(
    const unsigned long long* __restrict__ supm, const int* __restrict__ selcnt,
    unsigned long long* __restrict__ keepw)
{
  __shared__ unsigned long long rem[16];
  int g = blockIdx.x, l = threadIdx.x;
  if (l < 16) rem[l] = 0ULL;
  __syncthreads();
  int k = selcnt[g];
  for (int i = 0; i < k; ++i) {
    bool sup = (rem[i >> 6] >> (i & 63)) & 1ULL;
    __syncthreads();
    if (!sup && l < 16) rem[l] |= supm[((size_t)g*1024 + i)*16 + l];
    __syncthreads();
  }
  if (l < 16) keepw[g*16 + l] = ~rem[l];
}

// ---------------- per-image merge: packed-key bitonic sort, emit top-1000 ----------------
__global__ __launch_bounds__(1024) void final_kernel(
    const float* __restrict__ selv32, const int* __restrict__ selcnt,
    const unsigned long long* __restrict__ keepw, const float* __restrict__ boxesF,
    float* __restrict__ outB, float* __restrict__ outI)
{
  extern __shared__ unsigned long long S[];
  int img = blockIdx.x, tid = threadIdx.x;
  for (int t = tid; t < 8192; t += 1024) {
    unsigned long long key = 0ULL;
    if (t < 5000) {
      int lv = t / 1000, r = t - lv*1000;
      int g = img*5 + lv;
      if (r < selcnt[g] && ((keepw[g*16 + (r >> 6)] >> (r & 63)) & 1ULL)) {
        float sv = selv32[(size_t)g*1024 + r];
        // score desc, then slot (concat position) asc = stable argsort
        key = ((unsigned long long)fkey32(sv) << 32) |
              (unsigned long long)(0xFFFFFFFFu ^ (unsigned)t);
      }
    }
    S[t] = key;
  }
  __syncthreads();
  for (int k2 = 2; k2 <= 8192; k2 <<= 1)
    for (int j = k2 >> 1; j > 0; j >>= 1) {
      for (int t = tid; t < 4096; t += 1024) {
        int i = (t/j)*(2*j) + (t%j);
        int ix = i + j;
        bool up = ((i & k2) == 0);
        unsigned long long a = S[i], b = S[ix];
        if ((a < b) == up) { S[i] = b; S[ix] = a; }
      }
      __syncthreads();
    }
  for (int t = tid; t < 1000; t += 1024) {
    unsigned long long key = S[t];
    float4 bo = make_float4(0.f, 0.f, 0.f, 0.f);
    float ii = -1.f;
    if (key != 0ULL) {
      unsigned slot = 0xFFFFFFFFu ^ (unsigned)(key & 0xFFFFFFFFULL);
      int lv = slot / 1000, r = slot - lv*1000;
      const float* bp = boxesF + (((size_t)(img*5 + lv))*1024 + r)*4;
      bo = make_float4(bp[0], bp[1], bp[2], bp[3]);
      ii = (float)img;
    }
    ((float4*)outB)[img*1000 + t] = bo;
    outI[img*1000 + t] = ii;
  }
}

// ---------------- launch ----------------
extern "C" void kernel_launch(void* const* d_in, const int* in_sizes, int n_in,
                              void* d_out, int out_size, void* d_ws, size_t ws_size,
                              hipStream_t stream)
{
  const int LV_H[5]  = {160, 80, 40, 20, 10};
  const int LV_W[5]  = {240, 120, 60, 30, 15};
  const int LV_BASE_[5] = {0, 115200, 144000, 151200, 153000};

  const float* fm[5]; const float* pri[5];
  if (n_in >= 17 && in_sizes[1] == 460800) {
    for (int i = 0; i < 5; ++i) { fm[i] = (const float*)d_in[2*i]; pri[i] = (const float*)d_in[2*i+1]; }
  } else {
    for (int i = 0; i < 5; ++i) { fm[i] = (const float*)d_in[i]; pri[i] = (const float*)d_in[5+i]; }
  }
  const float* imsz  = (const float*)d_in[10];
  const float* convw = (const float*)d_in[11];
  const float* convb = (const float*)d_in[12];
  const float* logw  = (const float*)d_in[13];
  const float* logb  = (const float*)d_in[14];
  const float* regw  = (const float*)d_in[15];
  const float* regb  = (const float*)d_in[16];

  char* ws = (char*)d_ws;
  size_t off = 0;
  auto nxt = [&](size_t b) { size_t o = off; off = (off + b + 255) & ~(size_t)255; return o; };
  float* WT        = (float*)(ws + nxt((size_t)2304*256*4));
  float* logitsF   = (float*)(ws + nxt((size_t)2*TOTA*4));
  float* regF      = (float*)(ws + nxt((size_t)2*TOTA*4*4));
  unsigned* hist   = (unsigned*)(ws + nxt((size_t)NGRP*65536*4));
  int* meta        = (int*)(ws + nxt((size_t)NGRP*4));
  int* ccnt        = (int*)(ws + nxt((size_t)NGRP*4));
  unsigned long long* cand = (unsigned long long*)(ws + nxt((size_t)NGRP*CAND_CAP*8));
  float* sellk     = (float*)(ws + nxt((size_t)NGRP*1024*4));
  unsigned* seli   = (unsigned*)(ws + nxt((size_t)NGRP*1024*4));
  int* selcnt      = (int*)(ws + nxt((size_t)NGRP*4));
  float* selv32    = (float*)(ws + nxt((size_t)NGRP*1024*4));
  float* boxesF    = (float*)(ws + nxt((size_t)NGRP*1024*4*4));
  unsigned* maxbuf = (unsigned*)(ws + nxt(4));
  unsigned long long* supm  = (unsigned long long*)(ws + nxt((size_t)NGRP*1024*16*8));
  unsigned long long* keepw = (unsigned long long*)(ws + nxt((size_t)NGRP*16*8));
  if (off > ws_size) return;

  hipMemsetAsync(hist, 0, (size_t)NGRP*65536*4, stream);
  hipMemsetAsync(ccnt, 0, NGRP*4, stream);
  hipMemsetAsync(maxbuf, 0, 4, stream);

  transpose_w_kernel<<<2304, 256, 0, stream>>>(convw, WT);

  // fmap tensors are [N=2, C, H, W]; blockIdx.z selects the image.
  for (int lv = 0; lv < 5; ++lv) {
    if (lv == 0) {
      dim3 grid(LV_W[0]/48, LV_H[0], 2);                    // 5 x 160 x 2 = 1600 blocks
      conv_head_kernel<3><<<grid, 256, 0, stream>>>(
          WT, convb, logw, logb, regw, regb, fm[lv],
          logitsF, regF, LV_H[lv], LV_W[lv], LV_BASE_[lv]);
    } else {
      dim3 grid((LV_W[lv] + 31)/32, LV_H[lv], 2);
      conv_head_kernel<2><<<grid, 256, 0, stream>>>(
          WT, convb, logw, logb, regw, regb, fm[lv],
          logitsF, regF, LV_H[lv], LV_W[lv], LV_BASE_[lv]);
    }
  }
  int tot = 2*TOTA;
  hist_kernel<<<(tot + 255)/256, 256, 0, stream>>>(logitsF, hist);
  thresh_kernel<<<NGRP, 256, 0, stream>>>(hist, meta);
  collect_kernel<<<(tot + 255)/256, 256, 0, stream>>>(logitsF, meta, ccnt, cand);
  selsort_kernel<<<NGRP, 1024, 0, stream>>>(ccnt, cand, sellk, seli, selcnt);
  decode_kernel<<<NGRP, 1024, 0, stream>>>(seli, sellk, selcnt, regF, imsz,
      pri[0], pri[1], pri[2], pri[3], pri[4], boxesF, selv32);
  maxbox_kernel<<<(NGRP*1024*4 + 1023)/1024, 1024, 0, stream>>>(boxesF, maxbuf);
  mask_kernel<<<dim3(64, NGRP), 256, 0, stream>>>(boxesF, selcnt, maxbuf, supm);
  nms_scan_kernel<<<NGRP, 64, 0, stream>>>(supm, selcnt, keepw);
  final_kernel<<<2, 1024, 65536, stream>>>(selv32, selcnt, keepw, boxesF,
      (float*)d_out, (float*)d_out + 8000);
}

// Round 18
// 2639.284 us; speedup vs baseline: 2.4524x; 1.4634x over previous
//
#include <hip/hip_runtime.h>

#define TOTA 153450
#define NGRP 10
#define CK 4
#define CAND_CAP 4096
#define SENT (-3.0e38f)

// ---------------- helpers ----------------
__device__ __forceinline__ int lv_base(int lv) {
  switch (lv) { case 0: return 0; case 1: return 115200; case 2: return 144000;
                case 3: return 151200; default: return 153000; }
}
__device__ __forceinline__ int lv_of_anchor(int a) {
  if (a < 115200) return 0;
  if (a < 144000) return 1;
  if (a < 151200) return 2;
  if (a < 153000) return 3;
  return 4;
}
__device__ __forceinline__ int kk_of(int lv) { return lv == 4 ? 450 : 1000; }

// monotone u32 key for f32; larger key <=> larger float
__device__ __forceinline__ unsigned fkey32(float f) {
  unsigned u = __float_as_uint(f);
  return (u & 0x80000000u) ? ~u : (u | 0x80000000u);
}
__device__ __forceinline__ float inv_fkey32(unsigned k) {
  unsigned u = (k & 0x80000000u) ? (k & 0x7FFFFFFFu) : ~k;
  return __uint_as_float(u);
}

// correctly-rounded f32 transcendentals via f64
__device__ __forceinline__ float cr_expf(float x) { return (float)exp((double)x); }
__device__ __forceinline__ float cr_sigmoidf(float x) {
  float t = (float)exp(-(double)x);
  float d = 1.0f + t;
  return 1.0f / d;
}

// ---------------- one-time weight transpose: WT[k][co] = CW[co][k] ----------------
__global__ void transpose_w_kernel(const float* __restrict__ CW, float* __restrict__ WT) {
  int i = blockIdx.x*256 + threadIdx.x;
  if (i >= 2304*256) return;
  int co = i / 2304;
  int k  = i - co*2304;
  WT[(size_t)k*256 + co] = CW[i];
}

// ---------------- fused conv3x3 + bias + relu + 1x1 heads, ALL LEVELS ----------------
// NUMERICS BITWISE-FROZEN (R10-passing model): per-output FMA chain in
// k=(ci,ky,kx) order with kc=384 panel commits (plain adds); einsum-SOP
// heads. R18: ALL 5 levels x 2 images in ONE dispatch (3420 blocks) —
// eliminates grid starvation of small levels. Per-block code = R15 (PPT=2,
// the proven config); only the blockIdx -> (lv,tx,y,img) mapping is new.
#define PPT 2
#define SPT 32
#define XCOLS 34
__global__ __launch_bounds__(256) void conv_head_kernel(
    const float* __restrict__ WT, const float* __restrict__ CB,
    const float* __restrict__ LW, const float* __restrict__ LB,
    const float* __restrict__ RW, const float* __restrict__ RB,
    const float* __restrict__ f0, const float* __restrict__ f1,
    const float* __restrict__ f2, const float* __restrict__ f3,
    const float* __restrict__ f4,
    float* __restrict__ outLog, float* __restrict__ outReg)
{
#pragma clang fp contract(off)
  constexpr int SMEM0 = CK*9*256*4 + 3*CK*XCOLS*4;
  constexpr int SMEM = (SMEM0 > 31744) ? SMEM0 : 31744;
  __shared__ __align__(16) char smem[SMEM];
  float* WS = (float*)smem;                    // conv: [CK*9][256]
  float* XS = (float*)(smem + CK*9*256*4);     // conv: [3*CK][XCOLS]
  const int tid = threadIdx.x;
  const int sp = tid & 15;
  const int cg = tid >> 4;

  // ---- block -> (lv, tx, y) mapping; tiles/level = [1280,320,80,20,10] ----
  int bx = blockIdx.x;
  int lv, local;
  if (bx < 1280)      { lv = 0; local = bx; }
  else if (bx < 1600) { lv = 1; local = bx - 1280; }
  else if (bx < 1680) { lv = 2; local = bx - 1600; }
  else if (bx < 1700) { lv = 3; local = bx - 1680; }
  else                { lv = 4; local = bx - 1700; }
  const int TXN[5] = {8, 4, 2, 1, 1};
  const int LH[5]  = {160, 80, 40, 20, 10};
  const int LW_[5] = {240, 120, 60, 30, 15};
  int tx = local % TXN[lv];
  int y  = local / TXN[lv];
  int H = LH[lv], W = LW_[lv];
  int abase = lv_base(lv);
  const float* Xb;
  switch (lv) { case 0: Xb = f0; break; case 1: Xb = f1; break; case 2: Xb = f2; break;
                case 3: Xb = f3; break; default: Xb = f4; }
  const int img = blockIdx.z;
  const float* X = Xb + (size_t)img*256*H*W;
  float* oLog = outLog + (size_t)img*TOTA;       // [2][TOTA]
  float* oReg = outReg + (size_t)img*TOTA*4;     // [2][TOTA*4]
  const int x0 = tx * SPT;

  float acc[PPT][16];
  float acc2[PPT][16];
#pragma unroll
  for (int p = 0; p < PPT; ++p)
#pragma unroll
    for (int i = 0; i < 16; ++i) { acc[p][i] = 0.f; acc2[p][i] = 0.f; }

  for (int c0 = 0; c0 < 256; c0 += CK) {
    __syncthreads();
    // coalesced weight staging: 2304 float4s
    {
      const float4* wsrc = (const float4*)(WT + (size_t)c0*9*256);
      float4* wdst = (float4*)WS;
#pragma unroll
      for (int r = 0; r < 9; ++r)
        wdst[r*256 + tid] = wsrc[r*256 + tid];
    }
    // input strip: XS[ry*CK+ci][col], col -> ix = x0+col-1, 3 rows halo
    for (int t = tid; t < 3*CK*XCOLS; t += 256) {
      int col = t % XCOLS; int r = t / XCOLS;
      int ci = r % CK, ry = r / CK;
      int ix = x0 + col - 1, iy = y + ry - 1;
      float v = 0.f;
      if (ix >= 0 && ix < W && iy >= 0 && iy < H)
        v = X[((c0+ci)*H + iy)*W + ix];
      XS[r*XCOLS + col] = v;
    }
    __syncthreads();
#pragma unroll
    for (int ci = 0; ci < CK; ++ci) {
      int ch9 = (c0 + ci) * 9;
#pragma unroll
      for (int k9 = 0; k9 < 9; ++k9) {
        int kglob = ch9 + k9;
        if (kglob == 384 || kglob == 768 || kglob == 1152 ||
            kglob == 1536 || kglob == 1920) {
#pragma unroll
          for (int p = 0; p < PPT; ++p)
#pragma unroll
            for (int i = 0; i < 16; ++i) { acc2[p][i] = acc2[p][i] + acc[p][i]; acc[p][i] = 0.f; }
        }
        int ky = k9 / 3, kx = k9 - ky*3;
        const float* xb = &XS[(ky*CK + ci)*XCOLS + sp + kx];
        float dxv[PPT];
#pragma unroll
        for (int p = 0; p < PPT; ++p) dxv[p] = xb[p*16];
        const float* wr = &WS[(ci*9 + k9)*256 + cg*16];
#pragma unroll
        for (int i = 0; i < 16; i += 4) {
          float4 w4 = *(const float4*)(wr + i);
#pragma unroll
          for (int p = 0; p < PPT; ++p) {
            acc[p][i+0] = fmaf(w4.x, dxv[p], acc[p][i+0]);
            acc[p][i+1] = fmaf(w4.y, dxv[p], acc[p][i+1]);
            acc[p][i+2] = fmaf(w4.z, dxv[p], acc[p][i+2]);
            acc[p][i+3] = fmaf(w4.w, dxv[p], acc[p][i+3]);
          }
        }
      }
    }
  }
  __syncthreads();
  // head phase: PPT passes of 16 pixels; HS[256][16] + HWT[15][256]
  float* HS = (float*)smem;                    // 16384 B
  float* HWT = (float*)(smem + 16384);         // 15360 B
  for (int t = tid; t < 15*256; t += 256) {
    int o = t >> 8, c = t & 255;
    HWT[t] = (o < 3) ? LW[o*256 + c] : RW[(o-3)*256 + c];
  }
#pragma unroll
  for (int px = 0; px < PPT; ++px) {
    __syncthreads();
#pragma unroll
    for (int i = 0; i < 16; ++i) {
      float hsum = acc2[px][i] + acc[px][i];   // final panel commit
      float v = hsum + CB[cg*16 + i];
      HS[(cg*16 + i)*16 + sp] = v > 0.f ? v : 0.f;
    }
    __syncthreads();
    if (cg < 15) {
      const float* wr = &HWT[cg*256];
      float a2 = 0.f;
      for (int c = 0; c < 256; ++c) {
        float p = HS[c*16 + sp] * wr[c];   // separate rounding (no FMA)
        a2 = a2 + p;
      }
      int gx = x0 + px*16 + sp;
      if (gx < W) {
        int locg = y*W + gx;
        if (cg < 3) {
          oLog[abase + locg*3 + cg] = a2 + LB[cg];
        } else {
          int oo = cg - 3;
          oReg[(size_t)(abase + locg*3 + (oo >> 2))*4 + (oo & 3)] = a2 + RB[oo];
        }
      }
    }
  }
}

// ---------------- fast exact top-k: hist -> thresh -> collect -> sort ----------------
__global__ void hist_kernel(const float* __restrict__ logits, unsigned* __restrict__ hist) {
  int i = blockIdx.x*256 + threadIdx.x;
  if (i >= 2*TOTA) return;
  int img = i / TOTA, a = i - img*TOTA;
  int lv = lv_of_anchor(a);
  unsigned k = fkey32(logits[i]);
  atomicAdd(&hist[(size_t)(img*5+lv)*65536 + (k >> 16)], 1u);
}

__global__ __launch_bounds__(256) void thresh_kernel(const unsigned* __restrict__ hist,
                                                     int* __restrict__ meta) {
  int g = blockIdx.x;
  const unsigned* hg = hist + (size_t)g*65536;
  __shared__ unsigned part[256];
  int tid = threadIdx.x;
  unsigned s = 0;
  for (int b = tid*256; b < tid*256 + 256; ++b) s += hg[b];
  part[tid] = s;
  __syncthreads();
  if (tid == 0) {
    int k = kk_of(g % 5);
    unsigned cum = 0; int gsel = 0;
    for (int j = 255; j >= 0; --j) {
      if (cum + part[j] >= (unsigned)k) { gsel = j; break; }
      cum += part[j];
    }
    int B = gsel*256;
    for (int b = gsel*256 + 255; b >= gsel*256; --b) {
      unsigned h = hg[b];
      if (cum + h >= (unsigned)k) { B = b; break; }
      cum += h;
    }
    meta[g] = B;
  }
}

__global__ void collect_kernel(const float* __restrict__ logits, const int* __restrict__ meta,
                               int* __restrict__ ccnt, unsigned long long* __restrict__ cand) {
  int i = blockIdx.x*256 + threadIdx.x;
  if (i >= 2*TOTA) return;
  int img = i / TOTA, a = i - img*TOTA;
  int lv = lv_of_anchor(a);
  int g = img*5 + lv;
  unsigned k = fkey32(logits[i]);
  if ((int)(k >> 16) >= meta[g]) {
    int p = atomicAdd(&ccnt[g], 1);
    if (p < CAND_CAP) {
      unsigned idx = (unsigned)(a - lv_base(lv));
      cand[(size_t)g*CAND_CAP + p] =
          ((unsigned long long)k << 32) | (unsigned long long)(0xFFFFFFFFu ^ idx);
    }
  }
}

// bitonic sort candidates desc (key desc, idx asc); emit top-k (logit, idx)
__global__ __launch_bounds__(1024) void selsort_kernel(
    const int* __restrict__ ccnt, const unsigned long long* __restrict__ cand,
    float* __restrict__ sellk, unsigned* __restrict__ seli, int* __restrict__ selcnt)
{
  __shared__ unsigned long long KS[CAND_CAP];
  int g = blockIdx.x, tid = threadIdx.x;
  int n = ccnt[g]; if (n > CAND_CAP) n = CAND_CAP;
  for (int t = tid; t < CAND_CAP; t += 1024)
    KS[t] = (t < n) ? cand[(size_t)g*CAND_CAP + t] : 0ULL;
  __syncthreads();
  for (int k2 = 2; k2 <= CAND_CAP; k2 <<= 1)
    for (int j = k2 >> 1; j > 0; j >>= 1) {
      for (int t = tid; t < CAND_CAP/2; t += 1024) {
        int i = (t/j)*(2*j) + (t%j);
        int ix = i + j;
        bool up = ((i & k2) == 0);
        unsigned long long a = KS[i], b = KS[ix];
        if ((a < b) == up) { KS[i] = b; KS[ix] = a; }
      }
      __syncthreads();
    }
  int k = kk_of(g % 5);
  if (tid == 0) selcnt[g] = k;
  for (int t = tid; t < 1024; t += 1024) {
    if (t < k) {
      unsigned long long e = KS[t];
      sellk[(size_t)g*1024 + t] = inv_fkey32((unsigned)(e >> 32));
      seli[(size_t)g*1024 + t] = 0xFFFFFFFFu ^ (unsigned)(e & 0xFFFFFFFFULL);
    } else {
      sellk[(size_t)g*1024 + t] = SENT;
      seli[(size_t)g*1024 + t] = 0u;
    }
  }
}

// ---------------- f32 decode + clamp (per-op rounding, CR exp) + s32 scores ----------------
__global__ __launch_bounds__(1024) void decode_kernel(
    const unsigned* __restrict__ seli, const float* __restrict__ sellk,
    const int* __restrict__ selcnt,
    const float* __restrict__ reg, const float* __restrict__ imsz,
    const float* __restrict__ p0, const float* __restrict__ p1, const float* __restrict__ p2,
    const float* __restrict__ p3, const float* __restrict__ p4,
    float* __restrict__ boxesF, float* __restrict__ selv32)
{
#pragma clang fp contract(off)
  int g = blockIdx.x, t = threadIdx.x;
  int img = g/5, lv = g - img*5;
  int k = selcnt[g];
  float b0 = 0, b1 = 0, b2 = 0, b3 = 0;
  float sv = SENT;
  if (t < k) {
    unsigned aidx = seli[(size_t)g*1024 + t];
    const float* pr;
    switch (lv) { case 0: pr = p0; break; case 1: pr = p1; break; case 2: pr = p2; break;
                  case 3: pr = p3; break; default: pr = p4; }
    pr += (size_t)aidx*4;
    const float* rg = reg + ((size_t)img*TOTA + lv_base(lv) + aidx)*4;
    float q0 = pr[0], q1 = pr[1], q2 = pr[2], q3 = pr[3];
    float pw = q2 - q0, ph = q3 - q1;
    float pcx = q0 + 0.5f*pw, pcy = q1 + 0.5f*ph;
    float t0 = rg[0]*pw, t1 = rg[1]*ph;
    float cx = pcx + t0, cy = pcy + t1;
    float e2 = cr_expf(rg[2]);
    float e3 = cr_expf(rg[3]);
    float bw = pw*e2, bh = ph*e3;
    float x1 = cx - bw*0.5f, y1 = cy - bh*0.5f, x2 = cx + bw*0.5f, y2 = cy + bh*0.5f;
    float mh = imsz[img*2 + 0], mw = imsz[img*2 + 1];
    b0 = fminf(fmaxf(x1, 0.f), mw);
    b1 = fminf(fmaxf(y1, 0.f), mh);
    b2 = fminf(fmaxf(x2, 0.f), mw);
    b3 = fminf(fmaxf(y2, 0.f), mh);
    sv = cr_sigmoidf(sellk[(size_t)g*1024 + t]);
  }
  float* o = boxesF + ((size_t)g*1024 + t)*4;
  o[0] = b0; o[1] = b1; o[2] = b2; o[3] = b3;
  selv32[(size_t)g*1024 + t] = sv;
}

// ---------------- global max over clamped boxes (all >= 0) ----------------
__global__ void maxbox_kernel(const float* __restrict__ boxesF, unsigned* __restrict__ maxbuf) {
  int i = blockIdx.x*1024 + threadIdx.x;
  if (i < NGRP*1024*4) {
    float v = boxesF[i];
    atomicMax(maxbuf, __float_as_uint(v));
  }
}

// ---------------- NMS: parallel IoU bitmask (same f32 exprs) + serial scan ----------------
__global__ __launch_bounds__(256) void mask_kernel(
    const float* __restrict__ boxesF, const int* __restrict__ selcnt,
    const unsigned* __restrict__ maxbuf, unsigned long long* __restrict__ supm)
{
#pragma clang fp contract(off)
  __shared__ float4 BS[1024];
  __shared__ float AR[1024];
  int g = blockIdx.y;
  int i = blockIdx.x*16 + (threadIdx.x >> 4);
  int w = threadIdx.x & 15;
  int img = g/5, lv = g - img*5;
  int k = selcnt[g];
  float mx1 = __uint_as_float(*maxbuf) + 1.0f;
  float offv = (float)(img*10 + lv) * mx1;
  for (int t = threadIdx.x; t < 1024; t += 256) {
    float4 b = ((const float4*)boxesF)[(size_t)g*1024 + t];
    b.x = b.x + offv; b.y = b.y + offv; b.z = b.z + offv; b.w = b.w + offv;
    BS[t] = b;
    float dw = b.z - b.x, dh = b.w - b.y;
    AR[t] = dw*dh;
  }
  __syncthreads();
  unsigned long long m = 0ULL;
  if (i < k) {
    float4 bi = BS[i]; float ai = AR[i];
    int jbase = w*64;
    for (int jj = 0; jj < 64; ++jj) {
      int j = jbase + jj;
      if (j > i && j < k) {
        float4 bj = BS[j];
        float ix1 = fmaxf(bi.x, bj.x), iy1 = fmaxf(bi.y, bj.y);
        float ix2 = fminf(bi.z, bj.z), iy2 = fminf(bi.w, bj.w);
        float d1 = fmaxf(ix2 - ix1, 0.f), d2 = fmaxf(iy2 - iy1, 0.f);
        float inter = d1*d2;
        float un = ai + AR[j];
        un = un - inter;
        float iou = inter / fmaxf(un, 1e-9f);
        if (iou > 0.7f) m |= (1ULL << jj);
      }
    }
  }
  supm[((size_t)g*1024 + i)*16 + w] = m;
}

__global__ __launch_bounds__(64) void nms_scan_kernel(
    const unsigned long long* __restrict__ supm, const int* __restrict__ selcnt,
    unsigned long long* __restrict__ keepw)
{
  __shared__ unsigned long long rem[16];
  int g = blockIdx.x, l = threadIdx.x;
  if (l < 16) rem[l] = 0ULL;
  __syncthreads();
  int k = selcnt[g];
  for (int i = 0; i < k; ++i) {
    bool sup = (rem[i >> 6] >> (i & 63)) & 1ULL;
    __syncthreads();
    if (!sup && l < 16) rem[l] |= supm[((size_t)g*1024 + i)*16 + l];
    __syncthreads();
  }
  if (l < 16) keepw[g*16 + l] = ~rem[l];
}

// ---------------- per-image merge: packed-key bitonic sort, emit top-1000 ----------------
__global__ __launch_bounds__(1024) void final_kernel(
    const float* __restrict__ selv32, const int* __restrict__ selcnt,
    const unsigned long long* __restrict__ keepw, const float* __restrict__ boxesF,
    float* __restrict__ outB, float* __restrict__ outI)
{
  extern __shared__ unsigned long long S[];
  int img = blockIdx.x, tid = threadIdx.x;
  for (int t = tid; t < 8192; t += 1024) {
    unsigned long long key = 0ULL;
    if (t < 5000) {
      int lv = t / 1000, r = t - lv*1000;
      int g = img*5 + lv;
      if (r < selcnt[g] && ((keepw[g*16 + (r >> 6)] >> (r & 63)) & 1ULL)) {
        float sv = selv32[(size_t)g*1024 + r];
        // score desc, then slot (concat position) asc = stable argsort
        key = ((unsigned long long)fkey32(sv) << 32) |
              (unsigned long long)(0xFFFFFFFFu ^ (unsigned)t);
      }
    }
    S[t] = key;
  }
  __syncthreads();
  for (int k2 = 2; k2 <= 8192; k2 <<= 1)
    for (int j = k2 >> 1; j > 0; j >>= 1) {
      for (int t = tid; t < 4096; t += 1024) {
        int i = (t/j)*(2*j) + (t%j);
        int ix = i + j;
        bool up = ((i & k2) == 0);
        unsigned long long a = S[i], b = S[ix];
        if ((a < b) == up) { S[i] = b; S[ix] = a; }
      }
      __syncthreads();
    }
  for (int t = tid; t < 1000; t += 1024) {
    unsigned long long key = S[t];
    float4 bo = make_float4(0.f, 0.f, 0.f, 0.f);
    float ii = -1.f;
    if (key != 0ULL) {
      unsigned slot = 0xFFFFFFFFu ^ (unsigned)(key & 0xFFFFFFFFULL);
      int lv = slot / 1000, r = slot - lv*1000;
      const float* bp = boxesF + (((size_t)(img*5 + lv))*1024 + r)*4;
      bo = make_float4(bp[0], bp[1], bp[2], bp[3]);
      ii = (float)img;
    }
    ((float4*)outB)[img*1000 + t] = bo;
    outI[img*1000 + t] = ii;
  }
}

// ---------------- launch ----------------
extern "C" void kernel_launch(void* const* d_in, const int* in_sizes, int n_in,
                              void* d_out, int out_size, void* d_ws, size_t ws_size,
                              hipStream_t stream)
{
  const float* fm[5]; const float* pri[5];
  if (n_in >= 17 && in_sizes[1] == 460800) {
    for (int i = 0; i < 5; ++i) { fm[i] = (const float*)d_in[2*i]; pri[i] = (const float*)d_in[2*i+1]; }
  } else {
    for (int i = 0; i < 5; ++i) { fm[i] = (const float*)d_in[i]; pri[i] = (const float*)d_in[5+i]; }
  }
  const float* imsz  = (const float*)d_in[10];
  const float* convw = (const float*)d_in[11];
  const float* convb = (const float*)d_in[12];
  const float* logw  = (const float*)d_in[13];
  const float* logb  = (const float*)d_in[14];
  const float* regw  = (const float*)d_in[15];
  const float* regb  = (const float*)d_in[16];

  char* ws = (char*)d_ws;
  size_t off = 0;
  auto nxt = [&](size_t b) { size_t o = off; off = (off + b + 255) & ~(size_t)255; return o; };
  float* WT        = (float*)(ws + nxt((size_t)2304*256*4));
  float* logitsF   = (float*)(ws + nxt((size_t)2*TOTA*4));
  float* regF      = (float*)(ws + nxt((size_t)2*TOTA*4*4));
  unsigned* hist   = (unsigned*)(ws + nxt((size_t)NGRP*65536*4));
  int* meta        = (int*)(ws + nxt((size_t)NGRP*4));
  int* ccnt        = (int*)(ws + nxt((size_t)NGRP*4));
  unsigned long long* cand = (unsigned long long*)(ws + nxt((size_t)NGRP*CAND_CAP*8));
  float* sellk     = (float*)(ws + nxt((size_t)NGRP*1024*4));
  unsigned* seli   = (unsigned*)(ws + nxt((size_t)NGRP*1024*4));
  int* selcnt      = (int*)(ws + nxt((size_t)NGRP*4));
  float* selv32    = (float*)(ws + nxt((size_t)NGRP*1024*4));
  float* boxesF    = (float*)(ws + nxt((size_t)NGRP*1024*4*4));
  unsigned* maxbuf = (unsigned*)(ws + nxt(4));
  unsigned long long* supm  = (unsigned long long*)(ws + nxt((size_t)NGRP*1024*16*8));
  unsigned long long* keepw = (unsigned long long*)(ws + nxt((size_t)NGRP*16*8));
  if (off > ws_size) return;

  hipMemsetAsync(hist, 0, (size_t)NGRP*65536*4, stream);
  hipMemsetAsync(ccnt, 0, NGRP*4, stream);
  hipMemsetAsync(maxbuf, 0, 4, stream);

  transpose_w_kernel<<<2304, 256, 0, stream>>>(convw, WT);

  // ONE dispatch: 1710 tiles (all levels) x 2 images.
  {
    dim3 grid(1710, 1, 2);
    conv_head_kernel<<<grid, 256, 0, stream>>>(
        WT, convb, logw, logb, regw, regb,
        fm[0], fm[1], fm[2], fm[3], fm[4],
        logitsF, regF);
  }
  int tot = 2*TOTA;
  hist_kernel<<<(tot + 255)/256, 256, 0, stream>>>(logitsF, hist);
  thresh_kernel<<<NGRP, 256, 0, stream>>>(hist, meta);
  collect_kernel<<<(tot + 255)/256, 256, 0, stream>>>(logitsF, meta, ccnt, cand);
  selsort_kernel<<<NGRP, 1024, 0, stream>>>(ccnt, cand, sellk, seli, selcnt);
  decode_kernel<<<NGRP, 1024, 0, stream>>>(seli, sellk, selcnt, regF, imsz,
      pri[0], pri[1], pri[2], pri[3], pri[4], boxesF, selv32);
  maxbox_kernel<<<(NGRP*1024*4 + 1023)/1024, 1024, 0, stream>>>(boxesF, maxbuf);
  mask_kernel<<<dim3(64, NGRP), 256, 0, stream>>>(boxesF, selcnt, maxbuf, supm);
  nms_scan_kernel<<<NGRP, 64, 0, stream>>>(supm, selcnt, keepw);
  final_kernel<<<2, 1024, 65536, stream>>>(selv32, selcnt, keepw, boxesF,
      (float*)d_out, (float*)d_out + 8000);
}